// Round 4
// baseline (301.395 us; speedup 1.0000x reference)
//
#include <hip/hip_runtime.h>
#include <hip/hip_bf16.h>

typedef __attribute__((ext_vector_type(8))) short short8;
typedef __attribute__((ext_vector_type(4))) float floatx4;
typedef __attribute__((ext_vector_type(4))) unsigned short ushort4v;
typedef __attribute__((ext_vector_type(8))) unsigned short ushort8v;
typedef __attribute__((ext_vector_type(2))) unsigned int uint2v;
typedef __attribute__((ext_vector_type(4))) unsigned int uint4v;

#define NN 10000
#define E0 160000
#define ETOT (E0 + NN)
#define IN_DIM 512
#define HID1 1024   /* HEADS*HID = 8*128 */
#define EMB 256
#define MPAD 10112  /* 79 * 128 */
#define NX (NN * IN_DIM)
#define NW1 (IN_DIM * HID1)
#define NW2 (HID1 * EMB)
#define DETB 625    /* E0/256 detect blocks in probe_kernel */

__device__ __forceinline__ float bf2f(unsigned short u) {
    unsigned v = ((unsigned)u) << 16;
    float f;
    __builtin_memcpy(&f, &v, 4);
    return f;
}
__device__ __forceinline__ float bflo(unsigned v) {
    unsigned x = v << 16;
    float f; __builtin_memcpy(&f, &x, 4);
    return f;
}
__device__ __forceinline__ float bfhi(unsigned v) {
    unsigned x = v & 0xffff0000u;
    float f; __builtin_memcpy(&f, &x, 4);
    return f;
}
__device__ __forceinline__ unsigned short f2bf(float f) {
    unsigned u;
    __builtin_memcpy(&u, &f, 4);
    unsigned lsb = (u >> 16) & 1;
    u += 0x7fff + lsb;           // round-to-nearest-even
    return (unsigned short)(u >> 16);
}
__device__ __forceinline__ unsigned packbf(float lo, float hi) {
    return (unsigned)f2bf(lo) | ((unsigned)f2bf(hi) << 16);
}
__device__ __forceinline__ float loadf(const void* p, size_t i, int isf32) {
    if (isf32) return ((const float*)p)[i];
    return bf2f(((const unsigned short*)p)[i]);
}
__device__ __forceinline__ float lrelu(float e) { return e > 0.f ? e : 0.2f * e; }

// ---------------- zero fill ----------------
__global__ void zero_kernel(int* p, int n) {
    int i = blockIdx.x * 256 + threadIdx.x;
    if (i < n) p[i] = 0;
}

// ---------------- fused probe: edge dtype (blocks 0..DETB-1) + float dtype (block DETB) ----------------
__global__ __launch_bounds__(256) void probe_kernel(const int* ei32, const unsigned* xw,
                                                    int* eflag, int* isf32) {
    int t = threadIdx.x;
    if (blockIdx.x < DETB) {
        int i = blockIdx.x * 256 + t;
        int v = 0;
        int idx = 2 * i + 1;
        if (idx < 2 * E0) v = ei32[idx];
        unsigned long long any = __ballot(v != 0);
        if (any && (t & 63) == 0) atomicOr(eflag, 1);
    } else {
        __shared__ int cnt[256];
        int c = 0;
        #pragma unroll
        for (int j = 0; j < 16; ++j) {
            unsigned w = xw[t * 16 + j];
            int ex = (w >> 7) & 0xFF;
            if (ex >= 110 && ex <= 135) c++;
        }
        cnt[t] = c;
        __syncthreads();
        for (int off = 128; off > 0; off >>= 1) {
            if (t < off) cnt[t] += cnt[t + off];
            __syncthreads();
        }
        if (t == 0) *isf32 = (cnt[0] < 2048) ? 1 : 0;
    }
}

__device__ __forceinline__ int load_edge(const void* ei, long long idx, int m32) {
    if (m32) return ((const int*)ei)[idx];
    return (int)(((const long long*)ei)[idx]);
}

// ---------------- CSR build ----------------
__global__ void count_kernel(const void* ei, const int* flag, int* counts) {
    int e = blockIdx.x * 256 + threadIdx.x;
    if (e < E0) {
        int m32 = (*flag != 0);
        int d = load_edge(ei, (long long)E0 + e, m32);
        if (d >= 0 && d < NN) atomicAdd(&counts[d], 1);
    }
}

// shfl-based block scan: 1024 threads x 10 values, 2 barriers total.
__global__ __launch_bounds__(1024) void scan_kernel(const int* counts, int* offsets, int* cursor) {
    __shared__ int wsum[16];
    int t = threadIdx.x;
    int lane = t & 63, wv = t >> 6;
    int base = t * 10;
    int local[10];
    int s = 0;
    #pragma unroll
    for (int j = 0; j < 10; ++j) {
        int idx = base + j;
        int v = (idx < NN) ? (counts[idx] + 1) : 0;  // +1 self loop
        local[j] = v; s += v;
    }
    // inclusive wave scan of s
    int v = s;
    #pragma unroll
    for (int d = 1; d < 64; d <<= 1) {
        int o = __shfl_up(v, d, 64);
        if (lane >= d) v += o;
    }
    if (lane == 63) wsum[wv] = v;
    __syncthreads();
    if (t < 16) {
        int w = wsum[t];
        #pragma unroll
        for (int d = 1; d < 16; d <<= 1) {
            int o = __shfl_up(w, d, 16);
            if (t >= d) w += o;
        }
        wsum[t] = w;
    }
    __syncthreads();
    int woff = (wv == 0) ? 0 : wsum[wv - 1];
    int run = woff + v - s;   // exclusive prefix for this thread
    #pragma unroll
    for (int j = 0; j < 10; ++j) {
        int idx = base + j;
        if (idx < NN) { offsets[idx] = run; cursor[idx] = run; run += local[j]; }
    }
    if (t == 1023) offsets[NN] = wsum[15];
}

__global__ void scatter_kernel(const void* ei, const int* flag, int* cursor, int* csr_src) {
    int e = blockIdx.x * 256 + threadIdx.x;
    if (e >= ETOT) return;
    int m32 = (*flag != 0);
    int s, d;
    if (e < E0) { s = load_edge(ei, e, m32); d = load_edge(ei, (long long)E0 + e, m32); }
    else { s = d = e - E0; }
    if (s < 0) s = 0; if (s >= NN) s = NN - 1;
    if (d < 0) d = 0; if (d >= NN) d = NN - 1;
    int pos = atomicAdd(&cursor[d], 1);
    if (pos >= 0 && pos < ETOT) csr_src[pos] = s;
}

// ---------------- fused fp32->bf16 conversions (x, W1^T, W2^T in one launch) ----------------
__global__ void convall_kernel(const void* x, const void* W1, const void* W2,
                               unsigned short* xb, unsigned short* W1t, unsigned short* W2t,
                               const int* isf32)
{
    int i = blockIdx.x * 256 + threadIdx.x;
    int f = *isf32;
    if (i < NX) { xb[i] = f2bf(loadf(x, i, f)); return; }
    i -= NX;
    if (i < NW1) {
        int r = i / HID1, c = i % HID1;
        W1t[(size_t)c * IN_DIM + r] = f2bf(loadf(W1, i, f));
        return;
    }
    i -= NW1;
    if (i < NW2) {
        int r = i / EMB, c = i % EMB;
        W2t[(size_t)c * HID1 + r] = f2bf(loadf(W2, i, f));
    }
}

// ---------------- m97-style MFMA GEMM: C[Mpad,N] = A[Mpad,K] * Bt[N,K]^T ----------------
// global_load_lds width=16 staging into linear [128][32] bf16 tiles; col16 XOR-swizzle
// applied on BOTH the global source (inverse) and the ds_read (forward) — rule 21.
template<bool OUTBF16>
__global__ __launch_bounds__(256) void gemm_tile(
    const unsigned short* __restrict__ A,
    const unsigned short* __restrict__ Bt,
    void* __restrict__ Cv,
    int N, int K)
{
    __shared__ unsigned short As[128 * 32];
    __shared__ unsigned short Bs[128 * 32];
    int t = threadIdx.x;
    int wave = t >> 6;
    int lane = t & 63;
    int quad = lane >> 4;
    int l16  = lane & 15;
    int mq = wave & 1, nq = wave >> 1;
    size_t mblk = (size_t)blockIdx.x * 128;
    size_t nblk = (size_t)blockIdx.y * 128;

    floatx4 acc[4][4];
    #pragma unroll
    for (int i = 0; i < 4; ++i)
        #pragma unroll
        for (int j = 0; j < 4; ++j)
            acc[i][j] = (floatx4){0.f, 0.f, 0.f, 0.f};

    const unsigned short* Abase = A + mblk * K;
    const unsigned short* Bbase = Bt + nblk * K;

    for (int kk = 0; kk < K; kk += 32) {
        __syncthreads();   // previous iteration's fragment reads done before overwrite
        #pragma unroll
        for (int j = 0; j < 2; ++j) {
            int chunk = (wave << 7) + (j << 6) + lane;
            int r  = chunk >> 2;
            int cs = (chunk & 3) ^ (r & 3);
            const unsigned short* ga = Abase + (size_t)r * K + kk + cs * 8;
            const unsigned short* gb = Bbase + (size_t)r * K + kk + cs * 8;
            __builtin_amdgcn_global_load_lds(
                (const __attribute__((address_space(1))) void*)ga,
                (__attribute__((address_space(3))) void*)(As + (size_t)((wave << 7) + (j << 6)) * 8),
                16, 0, 0);
            __builtin_amdgcn_global_load_lds(
                (const __attribute__((address_space(1))) void*)gb,
                (__attribute__((address_space(3))) void*)(Bs + (size_t)((wave << 7) + (j << 6)) * 8),
                16, 0, 0);
        }
        __syncthreads();

        short8 af[4], bf[4];
        #pragma unroll
        for (int i = 0; i < 4; ++i) {
            int ar = mq * 64 + i * 16 + l16;
            int br = nq * 64 + i * 16 + l16;
            af[i] = *(const short8*)(const void*)(As + ar * 32 + (quad ^ (ar & 3)) * 8);
            bf[i] = *(const short8*)(const void*)(Bs + br * 32 + (quad ^ (br & 3)) * 8);
        }
        #pragma unroll
        for (int i = 0; i < 4; ++i)
            #pragma unroll
            for (int j = 0; j < 4; ++j)
                acc[i][j] = __builtin_amdgcn_mfma_f32_16x16x32_bf16(af[i], bf[j], acc[i][j], 0, 0, 0);
    }

    size_t crow0 = mblk + mq * 64 + quad * 4;
    size_t ccol0 = nblk + nq * 64 + l16;
    #pragma unroll
    for (int i = 0; i < 4; ++i) {
        #pragma unroll
        for (int r = 0; r < 4; ++r) {
            size_t row = crow0 + i * 16 + r;
            size_t b = row * N + ccol0;
            #pragma unroll
            for (int j = 0; j < 4; ++j) {
                if (OUTBF16) ((unsigned short*)Cv)[b + j * 16] = f2bf(acc[i][j][r]);
                else         ((float*)Cv)[b + j * 16] = acc[i][j][r];
            }
        }
    }
}

// ---------------- alpha for layer 1 (bf16 h1): as1/ad1 [N,8] ----------------
// 256 threads x 4 cols; reduce within 32-thread head groups via shfl (no LDS/syncs).
__global__ __launch_bounds__(256) void alpha1_kernel(
    const unsigned short* __restrict__ h1,
    const void* __restrict__ a_src, const void* __restrict__ a_dst,
    const int* __restrict__ isf32,
    float* __restrict__ as1, float* __restrict__ ad1)
{
    int n = blockIdx.x, t = threadIdx.x;
    int f = *isf32;
    ushort4v hv = *(const ushort4v*)(const void*)(h1 + (size_t)n * HID1 + t * 4);
    float ps = 0.f, pd = 0.f;
    #pragma unroll
    for (int i = 0; i < 4; ++i) {
        float h = bf2f(hv[i]);
        ps += h * loadf(a_src, t * 4 + i, f);
        pd += h * loadf(a_dst, t * 4 + i, f);
    }
    #pragma unroll
    for (int off = 1; off < 32; off <<= 1) {
        ps += __shfl_xor(ps, off, 64);
        pd += __shfl_xor(pd, off, 64);
    }
    if ((t & 31) == 0) {
        int h = t >> 5;
        as1[n * 8 + h] = ps;
        ad1[n * 8 + h] = pd;
    }
}

// ---------------- layer-1 single-pass softmax-aggregate + ELU -> hmid bf16 ----------------
// 4 edge-groups x 64 threads x 16 cols: each wave owns ~4.25 edges -> one 4-deep batch
// covers nearly all of them (shortest possible serial chain at full TLP).
__global__ __launch_bounds__(256) void agg1_kernel(
    const unsigned short* __restrict__ h1, const int* __restrict__ offsets,
    const int* __restrict__ csr_src, const float* __restrict__ as1,
    const float* __restrict__ ad1, const void* __restrict__ b1,
    const int* __restrict__ isf32,
    unsigned short* __restrict__ hmid)
{
    int n = blockIdx.x, t = threadIdx.x;
    int f = *isf32;
    int beg = offsets[n], end = offsets[n + 1];
    if (beg < 0) beg = 0; if (end > ETOT) end = ETOT;
    int g = t >> 6;          // edge group 0..3 (one wave each)
    int u = t & 63;
    int c0 = u * 16;         // 16 cols per thread
    int hc = u >> 3;         // head = c0/128
    float ad = ad1[n * 8 + hc];
    const unsigned* rb = (const unsigned*)h1 + u * 8;   // + s*512 (u32 units)

    float den = 0.f;
    float acc[16];
    #pragma unroll
    for (int j = 0; j < 16; ++j) acc[j] = 0.f;

    int i = beg + g;
    // 4 edges in flight (group stride 4)
    for (; i + 12 < end; i += 16) {
        int s0 = csr_src[i];      s0 &= 0x7fffffff; if (s0 >= NN) s0 = 0;
        int s1 = csr_src[i + 4];  s1 &= 0x7fffffff; if (s1 >= NN) s1 = 0;
        int s2 = csr_src[i + 8];  s2 &= 0x7fffffff; if (s2 >= NN) s2 = 0;
        int s3 = csr_src[i + 12]; s3 &= 0x7fffffff; if (s3 >= NN) s3 = 0;
        uint4v a0 = *(const uint4v*)(const void*)(rb + (size_t)s0 * 512);
        uint4v b0 = *(const uint4v*)(const void*)(rb + (size_t)s0 * 512 + 4);
        uint4v a1 = *(const uint4v*)(const void*)(rb + (size_t)s1 * 512);
        uint4v b1v = *(const uint4v*)(const void*)(rb + (size_t)s1 * 512 + 4);
        uint4v a2 = *(const uint4v*)(const void*)(rb + (size_t)s2 * 512);
        uint4v b2v = *(const uint4v*)(const void*)(rb + (size_t)s2 * 512 + 4);
        uint4v a3 = *(const uint4v*)(const void*)(rb + (size_t)s3 * 512);
        uint4v b3v = *(const uint4v*)(const void*)(rb + (size_t)s3 * 512 + 4);
        float w0 = __expf(lrelu(as1[s0 * 8 + hc] + ad));
        float w1 = __expf(lrelu(as1[s1 * 8 + hc] + ad));
        float w2 = __expf(lrelu(as1[s2 * 8 + hc] + ad));
        float w3 = __expf(lrelu(as1[s3 * 8 + hc] + ad));
        den += (w0 + w1) + (w2 + w3);
        #pragma unroll
        for (int q = 0; q < 4; ++q) {
            acc[2 * q]      += (bflo(a0[q]) * w0 + bflo(a1[q]) * w1) + (bflo(a2[q]) * w2 + bflo(a3[q]) * w3);
            acc[2 * q + 1]  += (bfhi(a0[q]) * w0 + bfhi(a1[q]) * w1) + (bfhi(a2[q]) * w2 + bfhi(a3[q]) * w3);
            acc[8 + 2 * q]  += (bflo(b0[q]) * w0 + bflo(b1v[q]) * w1) + (bflo(b2v[q]) * w2 + bflo(b3v[q]) * w3);
            acc[9 + 2 * q]  += (bfhi(b0[q]) * w0 + bfhi(b1v[q]) * w1) + (bfhi(b2v[q]) * w2 + bfhi(b3v[q]) * w3);
        }
    }
    // 2 edges in flight
    for (; i + 4 < end; i += 8) {
        int s0 = csr_src[i];     s0 &= 0x7fffffff; if (s0 >= NN) s0 = 0;
        int s1 = csr_src[i + 4]; s1 &= 0x7fffffff; if (s1 >= NN) s1 = 0;
        uint4v a0 = *(const uint4v*)(const void*)(rb + (size_t)s0 * 512);
        uint4v b0 = *(const uint4v*)(const void*)(rb + (size_t)s0 * 512 + 4);
        uint4v a1 = *(const uint4v*)(const void*)(rb + (size_t)s1 * 512);
        uint4v b1v = *(const uint4v*)(const void*)(rb + (size_t)s1 * 512 + 4);
        float w0 = __expf(lrelu(as1[s0 * 8 + hc] + ad));
        float w1 = __expf(lrelu(as1[s1 * 8 + hc] + ad));
        den += w0 + w1;
        #pragma unroll
        for (int q = 0; q < 4; ++q) {
            acc[2 * q]      += bflo(a0[q]) * w0 + bflo(a1[q]) * w1;
            acc[2 * q + 1]  += bfhi(a0[q]) * w0 + bfhi(a1[q]) * w1;
            acc[8 + 2 * q]  += bflo(b0[q]) * w0 + bflo(b1v[q]) * w1;
            acc[9 + 2 * q]  += bfhi(b0[q]) * w0 + bfhi(b1v[q]) * w1;
        }
    }
    // tail single edge
    if (i < end) {
        int s0 = csr_src[i]; s0 &= 0x7fffffff; if (s0 >= NN) s0 = 0;
        uint4v a0 = *(const uint4v*)(const void*)(rb + (size_t)s0 * 512);
        uint4v b0 = *(const uint4v*)(const void*)(rb + (size_t)s0 * 512 + 4);
        float w0 = __expf(lrelu(as1[s0 * 8 + hc] + ad));
        den += w0;
        #pragma unroll
        for (int q = 0; q < 4; ++q) {
            acc[2 * q]      += bflo(a0[q]) * w0;
            acc[2 * q + 1]  += bfhi(a0[q]) * w0;
            acc[8 + 2 * q]  += bflo(b0[q]) * w0;
            acc[9 + 2 * q]  += bfhi(b0[q]) * w0;
        }
    }

    // combine the 4 edge groups (groups 1-3 park in LDS; stride 17 to avoid conflicts)
    __shared__ float sh[3][64][17];
    if (g) {
        #pragma unroll
        for (int j = 0; j < 16; ++j) sh[g - 1][u][j] = acc[j];
        sh[g - 1][u][16] = den;
    }
    __syncthreads();
    if (g == 0) {
        den += sh[0][u][16] + sh[1][u][16] + sh[2][u][16];
        float rden = 1.0f / fmaxf(den, 1e-30f);
        uint4v oA, oB;
        #pragma unroll
        for (int q = 0; q < 4; ++q) {
            float v0 = (acc[2 * q]     + sh[0][u][2 * q]     + sh[1][u][2 * q]     + sh[2][u][2 * q])     * rden + loadf(b1, c0 + 2 * q, f);
            float v1 = (acc[2 * q + 1] + sh[0][u][2 * q + 1] + sh[1][u][2 * q + 1] + sh[2][u][2 * q + 1]) * rden + loadf(b1, c0 + 2 * q + 1, f);
            v0 = v0 > 0.f ? v0 : (__expf(v0) - 1.0f);
            v1 = v1 > 0.f ? v1 : (__expf(v1) - 1.0f);
            oA[q] = packbf(v0, v1);
            float u0 = (acc[8 + 2 * q] + sh[0][u][8 + 2 * q] + sh[1][u][8 + 2 * q] + sh[2][u][8 + 2 * q]) * rden + loadf(b1, c0 + 8 + 2 * q, f);
            float u1 = (acc[9 + 2 * q] + sh[0][u][9 + 2 * q] + sh[1][u][9 + 2 * q] + sh[2][u][9 + 2 * q]) * rden + loadf(b1, c0 + 9 + 2 * q, f);
            u0 = u0 > 0.f ? u0 : (__expf(u0) - 1.0f);
            u1 = u1 > 0.f ? u1 : (__expf(u1) - 1.0f);
            oB[q] = packbf(u0, u1);
        }
        unsigned* hw = (unsigned*)hmid;
        *(uint4v*)(void*)(hw + (size_t)n * 512 + u * 8)     = oA;
        *(uint4v*)(void*)(hw + (size_t)n * 512 + u * 8 + 4) = oB;
    }
}

// ---------------- alpha for layer 2 (bf16 h2): as2/ad2 [N] ----------------
__global__ __launch_bounds__(256) void alpha2_kernel(
    const unsigned short* __restrict__ h2,
    const void* __restrict__ a_src2, const void* __restrict__ a_dst2,
    const int* __restrict__ isf32,
    float* __restrict__ as2, float* __restrict__ ad2)
{
    int n = blockIdx.x, t = threadIdx.x;
    int f = *isf32;
    float v = bf2f(h2[(size_t)n * EMB + t]);
    float ps = v * loadf(a_src2, t, f);
    float pd = v * loadf(a_dst2, t, f);
    __shared__ float rs[256], rdm[256];
    rs[t] = ps; rdm[t] = pd;
    __syncthreads();
    for (int off = 128; off > 0; off >>= 1) {
        if (t < off) { rs[t] += rs[t + off]; rdm[t] += rdm[t + off]; }
        __syncthreads();
    }
    if (t == 0) { as2[n] = rs[0]; ad2[n] = rdm[0]; }
}

// ---------------- layer-2 single-pass softmax-aggregate -> out fp32 ----------------
// 4 groups x 64 threads; 8B bf16 row loads; 4-deep unrolled edge loop.
__global__ __launch_bounds__(256) void agg2_kernel(
    const unsigned short* __restrict__ h2, const int* __restrict__ offsets,
    const int* __restrict__ csr_src, const float* __restrict__ as2,
    const float* __restrict__ ad2, const void* __restrict__ b2,
    const int* __restrict__ isf32,
    float* __restrict__ out)
{
    int n = blockIdx.x, t = threadIdx.x;
    int f = *isf32;
    int beg = offsets[n], end = offsets[n + 1];
    if (beg < 0) beg = 0; if (end > ETOT) end = ETOT;
    int g = t >> 6;          // edge group 0..3
    int u = t & 63;
    int c0 = u * 4;          // 4 cols per thread
    float adn = ad2[n];

    float den = 0.f;
    float acc[4];
    #pragma unroll
    for (int j = 0; j < 4; ++j) acc[j] = 0.f;

    int i = beg + g;
    for (; i + 12 < end; i += 16) {
        int s0 = csr_src[i];      s0 &= 0x7fffffff; if (s0 >= NN) s0 = 0;
        int s1 = csr_src[i + 4];  s1 &= 0x7fffffff; if (s1 >= NN) s1 = 0;
        int s2 = csr_src[i + 8];  s2 &= 0x7fffffff; if (s2 >= NN) s2 = 0;
        int s3 = csr_src[i + 12]; s3 &= 0x7fffffff; if (s3 >= NN) s3 = 0;
        ushort4v hv0 = *(const ushort4v*)(const void*)(h2 + (size_t)s0 * EMB + c0);
        ushort4v hv1 = *(const ushort4v*)(const void*)(h2 + (size_t)s1 * EMB + c0);
        ushort4v hv2 = *(const ushort4v*)(const void*)(h2 + (size_t)s2 * EMB + c0);
        ushort4v hv3 = *(const ushort4v*)(const void*)(h2 + (size_t)s3 * EMB + c0);
        float e0 = as2[s0] + adn;
        float e1 = as2[s1] + adn;
        float e2 = as2[s2] + adn;
        float e3 = as2[s3] + adn;
        e0 = e0 > 0.f ? e0 : 0.2f * e0;
        e1 = e1 > 0.f ? e1 : 0.2f * e1;
        e2 = e2 > 0.f ? e2 : 0.2f * e2;
        e3 = e3 > 0.f ? e3 : 0.2f * e3;
        float w0 = __expf(e0), w1 = __expf(e1), w2 = __expf(e2), w3 = __expf(e3);
        den += (w0 + w1) + (w2 + w3);
        #pragma unroll
        for (int j = 0; j < 4; ++j)
            acc[j] += (bf2f(hv0[j]) * w0 + bf2f(hv1[j]) * w1)
                    + (bf2f(hv2[j]) * w2 + bf2f(hv3[j]) * w3);
    }
    for (; i + 4 < end; i += 8) {
        int s0 = csr_src[i];     s0 &= 0x7fffffff; if (s0 >= NN) s0 = 0;
        int s1 = csr_src[i + 4]; s1 &= 0x7fffffff; if (s1 >= NN) s1 = 0;
        ushort4v hv0 = *(const ushort4v*)(const void*)(h2 + (size_t)s0 * EMB + c0);
        ushort4v hv1 = *(const ushort4v*)(const void*)(h2 + (size_t)s1 * EMB + c0);
        float e0 = as2[s0] + adn;
        float e1 = as2[s1] + adn;
        e0 = e0 > 0.f ? e0 : 0.2f * e0;
        e1 = e1 > 0.f ? e1 : 0.2f * e1;
        float w0 = __expf(e0), w1 = __expf(e1);
        den += w0 + w1;
        #pragma unroll
        for (int j = 0; j < 4; ++j)
            acc[j] += bf2f(hv0[j]) * w0 + bf2f(hv1[j]) * w1;
    }
    if (i < end) {
        int s0 = csr_src[i]; s0 &= 0x7fffffff; if (s0 >= NN) s0 = 0;
        ushort4v hv0 = *(const ushort4v*)(const void*)(h2 + (size_t)s0 * EMB + c0);
        float e0 = as2[s0] + adn;
        e0 = e0 > 0.f ? e0 : 0.2f * e0;
        float w0 = __expf(e0);
        den += w0;
        #pragma unroll
        for (int j = 0; j < 4; ++j) acc[j] += bf2f(hv0[j]) * w0;
    }

    __shared__ float accsh[4][64][5];   // padded to 5: kill 8-way bank conflict
    __shared__ float densh[4][64];
    #pragma unroll
    for (int j = 0; j < 4; ++j) accsh[g][u][j] = acc[j];
    densh[g][u] = den;
    __syncthreads();
    if (g == 0) {
        float dtot = densh[0][u] + densh[1][u] + densh[2][u] + densh[3][u];
        float rden = 1.0f / fmaxf(dtot, 1e-30f);
        floatx4 o;
        #pragma unroll
        for (int j = 0; j < 4; ++j) {
            float v = (accsh[0][u][j] + accsh[1][u][j] + accsh[2][u][j] + accsh[3][u][j]) * rden;
            o[j] = v + loadf(b2, c0 + j, f);
        }
        *(floatx4*)(void*)(out + (size_t)n * EMB + c0) = o;
    }
}

extern "C" void kernel_launch(void* const* d_in, const int* in_sizes, int n_in,
                              void* d_out, int out_size, void* d_ws, size_t ws_size,
                              hipStream_t stream)
{
    const void* x      = d_in[0];
    const void* edge   = d_in[1];
    const void* W1     = d_in[2];
    const void* a_src1 = d_in[3];
    const void* a_dst1 = d_in[4];
    const void* b1     = d_in[5];
    const void* W2     = d_in[6];
    const void* a_src2 = d_in[7];
    const void* a_dst2 = d_in[8];
    const void* b2     = d_in[9];
    float* out = (float*)d_out;

    char* ws = (char*)d_ws;
    size_t off = 0;
    auto alloc = [&](size_t bytes) -> void* {
        void* p = ws + off;
        off += (bytes + 255) & ~(size_t)255;
        return p;
    };
    int*            counts = (int*)alloc((NN + 2) * 4);   // counts[NN]=eflag, counts[NN+1]=isf32
    int*            offs   = (int*)alloc((NN + 1) * 4);
    int*            cursor = (int*)alloc(NN * 4);
    int*            csr    = (int*)alloc((size_t)ETOT * 4);
    float*          as1    = (float*)alloc((size_t)NN * 8 * 4);
    float*          ad1    = (float*)alloc((size_t)NN * 8 * 4);
    float*          as2    = (float*)alloc((size_t)NN * 4);
    float*          ad2    = (float*)alloc((size_t)NN * 4);
    unsigned short* xb     = (unsigned short*)alloc((size_t)MPAD * IN_DIM * 2);
    unsigned short* W1t    = (unsigned short*)alloc((size_t)IN_DIM * HID1 * 2);
    unsigned short* W2t    = (unsigned short*)alloc((size_t)HID1 * EMB * 2);
    unsigned short* h1b    = (unsigned short*)alloc((size_t)MPAD * HID1 * 2);
    unsigned short* hmid   = (unsigned short*)alloc((size_t)MPAD * HID1 * 2);
    unsigned short* h2b    = (unsigned short*)alloc((size_t)MPAD * EMB * 2);
    int* eflag = counts + NN;
    int* isf32 = counts + NN + 1;

    zero_kernel<<<(NN + 2 + 255) / 256, 256, 0, stream>>>(counts, NN + 2);
    probe_kernel<<<DETB + 1, 256, 0, stream>>>((const int*)edge, (const unsigned*)x, eflag, isf32);

    count_kernel<<<(E0 + 255) / 256, 256, 0, stream>>>(edge, eflag, counts);
    scan_kernel<<<1, 1024, 0, stream>>>(counts, offs, cursor);
    scatter_kernel<<<(ETOT + 255) / 256, 256, 0, stream>>>(edge, eflag, cursor, csr);

    // fused bf16 conversions: x row-major; W1,W2 transposed to [N][K]
    convall_kernel<<<(NX + NW1 + NW2 + 255) / 256, 256, 0, stream>>>(
        x, W1, W2, xb, W1t, W2t, isf32);

    // layer 1 GEMM (m97-style MFMA): h1b (bf16) = x @ W1
    dim3 g1(MPAD / 128, HID1 / 128);
    gemm_tile<true><<<g1, 256, 0, stream>>>(xb, W1t, h1b, HID1, IN_DIM);

    alpha1_kernel<<<NN, 256, 0, stream>>>(h1b, a_src1, a_dst1, isf32, as1, ad1);
    agg1_kernel<<<NN, 256, 0, stream>>>(h1b, offs, csr, as1, ad1, b1, isf32, hmid);

    // layer 2 GEMM (m97-style MFMA): h2b (bf16) = hmid @ W2
    dim3 g2(MPAD / 128, EMB / 128);
    gemm_tile<true><<<g2, 256, 0, stream>>>(hmid, W2t, h2b, EMB, HID1);

    alpha2_kernel<<<NN, 256, 0, stream>>>(h2b, a_src2, a_dst2, isf32, as2, ad2);
    agg2_kernel<<<NN, 256, 0, stream>>>(h2b, offs, csr, as2, ad2, b2, isf32, out);
}